// Round 1
// baseline (304.075 us; speedup 1.0000x reference)
//
#include <hip/hip_runtime.h>
#include <math.h>

// FactorizationMachine: out = sigmoid( X@fc_w + fc_b + 0.5*( sum_d (X@w)_d^2 - (X^2)@g ) )
// with g[f] = sum_d w[f,d]^2 (computed inline from the w row each thread loads anyway).
//
// B=4096 rows, F=50000 features, D=16 factors. Memory-bound on X (819 MB, read once).
// One block per 8 rows; threads stride over F in float4 chunks. w (3.2 MB) stays L2-resident.

constexpr int B_ROWS  = 4096;
constexpr int F_FEAT  = 50000;
constexpr int NF4     = F_FEAT / 4;   // 12500 float4 groups per row
constexpr int D_FAC   = 16;
constexpr int ROWS    = 8;            // rows per block (amortizes w loads 8x)
constexpr int THREADS = 256;
constexpr int NVAL    = ROWS * (D_FAC + 1); // 136 partial values per thread

__device__ __forceinline__ float f4c(const float4& v, int c) {
    // compile-time-folded component select (only used under full unroll)
    return c == 0 ? v.x : c == 1 ? v.y : c == 2 ? v.z : v.w;
}

__global__ __launch_bounds__(THREADS)
void fm_onehot_kernel(const float* __restrict__ X,
                      const float* __restrict__ fcw,
                      const float* __restrict__ fcb,
                      const float* __restrict__ W,
                      float* __restrict__ out)
{
    const int tid  = threadIdx.x;
    const int row0 = blockIdx.x * ROWS;

    const float4* X4  = reinterpret_cast<const float4*>(X);
    const float4* W4  = reinterpret_cast<const float4*>(W);
    const float4* FW4 = reinterpret_cast<const float4*>(fcw);

    float s[ROWS][D_FAC];
    float lin[ROWS];
#pragma unroll
    for (int r = 0; r < ROWS; ++r) {
        lin[r] = 0.f;
#pragma unroll
        for (int d = 0; d < D_FAC; ++d) s[r][d] = 0.f;
    }

    for (int f4 = tid; f4 < NF4; f4 += THREADS) {
        // X: 8 independent coalesced streams (one per row)
        float4 xv[ROWS];
#pragma unroll
        for (int r = 0; r < ROWS; ++r)
            xv[r] = X4[(size_t)(row0 + r) * NF4 + f4];

        // w rows for 4 consecutive features: 256 contiguous bytes per lane (L2-hit)
        float4 wv[16];
#pragma unroll
        for (int q = 0; q < 16; ++q)
            wv[q] = W4[(size_t)f4 * 16 + q];

        float4 fw = FW4[f4];

#pragma unroll
        for (int j = 0; j < 4; ++j) {          // 4 features in this float4 group
            float wd[D_FAC];
#pragma unroll
            for (int t = 0; t < D_FAC; ++t)
                wd[t] = f4c(wv[4 * j + (t >> 2)], t & 3);

            // g' = -0.5 * sum_d w_d^2  (amortized over 8 rows)
            float gp = 0.f;
#pragma unroll
            for (int t = 0; t < D_FAC; ++t) gp = fmaf(wd[t], wd[t], gp);
            gp *= -0.5f;

            const float fwj = f4c(fw, j);
#pragma unroll
            for (int r = 0; r < ROWS; ++r) {
                const float x  = f4c(xv[r], j);
                const float x2 = x * x;
                lin[r] = fmaf(x, fwj, lin[r]);
                lin[r] = fmaf(x2, gp, lin[r]);
#pragma unroll
                for (int t = 0; t < D_FAC; ++t)
                    s[r][t] = fmaf(x, wd[t], s[r][t]);
            }
        }
    }

    // ---- reduction: 64-lane butterfly, then cross-wave via LDS ----
    __shared__ float part[THREADS / 64][NVAL];
    __shared__ float red[NVAL];
    const int lane = tid & 63;
    const int wid  = tid >> 6;

#pragma unroll
    for (int r = 0; r < ROWS; ++r) {
#pragma unroll
        for (int t = 0; t < D_FAC; ++t) {
            float v = s[r][t];
#pragma unroll
            for (int m = 32; m >= 1; m >>= 1) v += __shfl_xor(v, m, 64);
            if (lane == 0) part[wid][r * 17 + t] = v;
        }
        float v = lin[r];
#pragma unroll
        for (int m = 32; m >= 1; m >>= 1) v += __shfl_xor(v, m, 64);
        if (lane == 0) part[wid][r * 17 + 16] = v;
    }
    __syncthreads();

    if (tid < NVAL) {
        red[tid] = part[0][tid] + part[1][tid] + part[2][tid] + part[3][tid];
    }
    __syncthreads();

    if (tid < ROWS) {
        float acc = red[tid * 17 + 16] + fcb[0];
        float ss  = 0.f;
#pragma unroll
        for (int t = 0; t < D_FAC; ++t) {
            const float sv = red[tid * 17 + t];
            ss = fmaf(sv, sv, ss);
        }
        const float logit = acc + 0.5f * ss;
        out[row0 + tid] = 1.0f / (1.0f + expf(-logit));
    }
}

extern "C" void kernel_launch(void* const* d_in, const int* in_sizes, int n_in,
                              void* d_out, int out_size, void* d_ws, size_t ws_size,
                              hipStream_t stream)
{
    const float* X   = (const float*)d_in[0];
    const float* fcw = (const float*)d_in[1];
    const float* fcb = (const float*)d_in[2];
    const float* W   = (const float*)d_in[3];
    float* out = (float*)d_out;

    dim3 grid(B_ROWS / ROWS);
    dim3 block(THREADS);
    hipLaunchKernelGGL(fm_onehot_kernel, grid, block, 0, stream,
                       X, fcw, fcb, W, out);
}

// Round 2
// 298.286 us; speedup vs baseline: 1.0194x; 1.0194x over previous
//
#include <hip/hip_runtime.h>
#include <math.h>

// FactorizationMachine: out = sigmoid( X@fc_w + fc_b + 0.5*( sum_d (X@w)_d^2 - (X^2)@g ) )
// with g[f] = sum_d w[f,d]^2 (computed inline from the w row each thread loads anyway).
//
// B=4096 rows, F=50000 features, D=16 factors. Memory-bound on X (819 MB, read once).
// One block per 8 rows; threads stride over F in float4 chunks.
//
// R1 change: X loads are NON-TEMPORAL (nt flag). X has zero reuse; without nt it
// streams through L2 and evicts W (3.2 MB, re-read by all 512 blocks = 1.6 GB
// logical), pushing W re-reads out to HBM (~2.3 GB total fetch, matched R0's
// 304 us at peak BW). With nt, W stays L2-resident; HBM fetch ~0.85 GB.

constexpr int B_ROWS  = 4096;
constexpr int F_FEAT  = 50000;
constexpr int NF4     = F_FEAT / 4;   // 12500 float4 groups per row
constexpr int D_FAC   = 16;
constexpr int ROWS    = 8;            // rows per block (amortizes w loads 8x)
constexpr int THREADS = 256;
constexpr int NVAL    = ROWS * (D_FAC + 1); // 136 partial values per block

typedef float f32x4 __attribute__((ext_vector_type(4)));

__device__ __forceinline__ f32x4 ntload4(const f32x4* p) {
    return __builtin_nontemporal_load(p);
}

__global__ __launch_bounds__(THREADS)
void fm_onehot_kernel(const float* __restrict__ X,
                      const float* __restrict__ fcw,
                      const float* __restrict__ fcb,
                      const float* __restrict__ W,
                      float* __restrict__ out)
{
    const int tid  = threadIdx.x;
    const int row0 = blockIdx.x * ROWS;

    const f32x4* X4  = reinterpret_cast<const f32x4*>(X);
    const f32x4* W4  = reinterpret_cast<const f32x4*>(W);
    const f32x4* FW4 = reinterpret_cast<const f32x4*>(fcw);

    float s[ROWS][D_FAC];
    float lin[ROWS];
#pragma unroll
    for (int r = 0; r < ROWS; ++r) {
        lin[r] = 0.f;
#pragma unroll
        for (int d = 0; d < D_FAC; ++d) s[r][d] = 0.f;
    }

    for (int f4 = tid; f4 < NF4; f4 += THREADS) {
        // X: 8 independent coalesced streams (one per row), non-temporal (no reuse)
        f32x4 xv[ROWS];
#pragma unroll
        for (int r = 0; r < ROWS; ++r)
            xv[r] = ntload4(&X4[(size_t)(row0 + r) * NF4 + f4]);

        // w rows for 4 consecutive features: 256 contiguous bytes per lane.
        // Normal (cached) loads — this is the L2-resident reuse data.
        f32x4 wv[16];
#pragma unroll
        for (int q = 0; q < 16; ++q)
            wv[q] = W4[(size_t)f4 * 16 + q];

        f32x4 fw = FW4[f4];

#pragma unroll
        for (int j = 0; j < 4; ++j) {          // 4 features in this float4 group
            float wd[D_FAC];
#pragma unroll
            for (int t = 0; t < D_FAC; ++t)
                wd[t] = wv[4 * j + (t >> 2)][t & 3];

            // g' = -0.5 * sum_d w_d^2  (amortized over 8 rows)
            float gp = 0.f;
#pragma unroll
            for (int t = 0; t < D_FAC; ++t) gp = fmaf(wd[t], wd[t], gp);
            gp *= -0.5f;

            const float fwj = fw[j];
#pragma unroll
            for (int r = 0; r < ROWS; ++r) {
                const float x  = xv[r][j];
                const float x2 = x * x;
                lin[r] = fmaf(x, fwj, lin[r]);
                lin[r] = fmaf(x2, gp, lin[r]);
#pragma unroll
                for (int t = 0; t < D_FAC; ++t)
                    s[r][t] = fmaf(x, wd[t], s[r][t]);
            }
        }
    }

    // ---- reduction: 64-lane butterfly, then cross-wave via LDS ----
    __shared__ float part[THREADS / 64][NVAL];
    __shared__ float red[NVAL];
    const int lane = tid & 63;
    const int wid  = tid >> 6;

#pragma unroll
    for (int r = 0; r < ROWS; ++r) {
#pragma unroll
        for (int t = 0; t < D_FAC; ++t) {
            float v = s[r][t];
#pragma unroll
            for (int m = 32; m >= 1; m >>= 1) v += __shfl_xor(v, m, 64);
            if (lane == 0) part[wid][r * 17 + t] = v;
        }
        float v = lin[r];
#pragma unroll
        for (int m = 32; m >= 1; m >>= 1) v += __shfl_xor(v, m, 64);
        if (lane == 0) part[wid][r * 17 + 16] = v;
    }
    __syncthreads();

    if (tid < NVAL) {
        red[tid] = part[0][tid] + part[1][tid] + part[2][tid] + part[3][tid];
    }
    __syncthreads();

    if (tid < ROWS) {
        float acc = red[tid * 17 + 16] + fcb[0];
        float ss  = 0.f;
#pragma unroll
        for (int t = 0; t < D_FAC; ++t) {
            const float sv = red[tid * 17 + t];
            ss = fmaf(sv, sv, ss);
        }
        const float logit = acc + 0.5f * ss;
        out[row0 + tid] = 1.0f / (1.0f + expf(-logit));
    }
}

extern "C" void kernel_launch(void* const* d_in, const int* in_sizes, int n_in,
                              void* d_out, int out_size, void* d_ws, size_t ws_size,
                              hipStream_t stream)
{
    const float* X   = (const float*)d_in[0];
    const float* fcw = (const float*)d_in[1];
    const float* fcb = (const float*)d_in[2];
    const float* W   = (const float*)d_in[3];
    float* out = (float*)d_out;

    dim3 grid(B_ROWS / ROWS);
    dim3 block(THREADS);
    hipLaunchKernelGGL(fm_onehot_kernel, grid, block, 0, stream,
                       X, fcw, fcb, W, out);
}